// Round 15
// baseline (38.108 us; speedup 1.0000x reference)
//
#include <hip/hip_runtime.h>
#include <math.h>

typedef _Float16 half8 __attribute__((ext_vector_type(8)));
typedef float floatx16 __attribute__((ext_vector_type(16)));
typedef unsigned int uintx4 __attribute__((ext_vector_type(4)));
typedef unsigned int uintx2 __attribute__((ext_vector_type(2)));

#define EPSV 1e-5f

// ---- workspace layout (bytes) ----
// 12 chunks of 14336 B, each = 6 w1-frags (6 KB) + 8 w2-frags (8 KB).
// Every frag = 64 lanes x 16 B in EXACT per-lane read order.
// ROOT CAUSE (R11/R12, confirmed): asm permlane32_swap was hazard-unsafe;
// builtin form passes in every schedule. LANE FLOW UNFROZEN.
// Perf ledger: R12 no-LDS 2w/SIMD = 33.1; R13 single-m-tile 3w/SIMD no-LDS
// = 40.0 (L1 thrash: >=3 distinct 14KB chunks vs 32KB L1); R14 LDS-staged
// 2w/SIMD = 33.1 (traffic/latency NOT binding at 2w). Diagnosis: matrix-pipe
// BUBBLES at 2 waves/SIMD (per-SIMD pipe busy ~1900 cyc/chunk vs ~6250 wall).
// THIS ROUND: combine R13 (single m-tile, verified) + R14 (LDS staging,
// verified): staging kills the L1 thrash, small regfile allows 3 waves/SIMD
// to fill the bubbles. 128 rows/block, grid 1024, LDS 28.7KB, 3 blocks/CU.
#define CHUNK_BYTES 14336
#define OFF_TILES 0
#define OFF_W3    (12 * CHUNK_BYTES)     // 172032 : 4 frags x 1 KB (w3 padded to 32 rows)
#define OFF_T2    (OFF_W3 + 4096)        // 64 f32 folded BN2 shift
#define OFF_OTAB  (OFF_T2 + 256)         // 29x4 f32 embedding-MLP table

typedef __attribute__((address_space(3))) char      lds_char;
typedef __attribute__((address_space(3))) unsigned  lds_uint;

// manual RTE f16 pack — HW-verified; do NOT swap for cvt_pkrtz (prev ERRATA)
__device__ __forceinline__ unsigned pk2(float a, float b) {
  _Float16 ha = (_Float16)a, hb = (_Float16)b;
  return (unsigned)__builtin_bit_cast(unsigned short, ha) |
         ((unsigned)__builtin_bit_cast(unsigned short, hb) << 16);
}
// permlane32_swap via BUILTIN (hazard-safe, R12/R13/R14-verified)
__device__ __forceinline__ void plswap(unsigned &a, unsigned &b) {
  uintx2 r = __builtin_amdgcn_permlane32_swap(a, b, false, false);
  a = r[0];
  b = r[1];
}
// Build GEMM2 B-operand fragment (k-chunk word q = elems hi*8+2q,+1) from 8
// C-layout values (rows (r&3)+8*(r>>2)+4*hi), applying relu + f16 cast.
__device__ __forceinline__ half8 mk_bfrag(float v0, float v1, float v2, float v3,
                                          float v4, float v5, float v6, float v7) {
  unsigned r0 = pk2(fmaxf(v0, 0.f), fmaxf(v1, 0.f));
  unsigned r1 = pk2(fmaxf(v2, 0.f), fmaxf(v3, 0.f));
  unsigned r2 = pk2(fmaxf(v4, 0.f), fmaxf(v5, 0.f));
  unsigned r3 = pk2(fmaxf(v6, 0.f), fmaxf(v7, 0.f));
  plswap(r0, r2);
  plswap(r1, r3);
  uintx4 uv = {r0, r1, r2, r3};
  return __builtin_bit_cast(half8, uv);
}
__device__ __forceinline__ floatx16 zero16() {
  floatx16 z;
  #pragma unroll
  for (int i = 0; i < 16; ++i) z[i] = 0.f;
  return z;
}

// ---------------- prep: fragment-stream weights + BN fold + otab ----------------
__global__ void prep_kernel(const float* __restrict__ E,  const float* __restrict__ W1,
                            const float* __restrict__ b1, const float* __restrict__ W2,
                            const float* __restrict__ b2,
                            const float* __restrict__ rW1, const float* __restrict__ rb1,
                            const float* __restrict__ g1,  const float* __restrict__ be1,
                            const float* __restrict__ m1,  const float* __restrict__ v1,
                            const float* __restrict__ rW2, const float* __restrict__ rb2,
                            const float* __restrict__ g2,  const float* __restrict__ be2,
                            const float* __restrict__ m2,  const float* __restrict__ v2,
                            const float* __restrict__ rW3, char* __restrict__ ws)
{
  _Float16* tiles = (_Float16*)(ws + OFF_TILES);
  _Float16* w3t   = (_Float16*)(ws + OFF_W3);
  float*    t2o   = (float*)(ws + OFF_T2);
  float*    otab  = (float*)(ws + OFF_OTAB);

  const int NTI = 12 * 7168;   // chunk f16 elements
  const int NW3 = 2048;
  const int NT2 = 64;
  const int NOT = 116;
  const int NT  = NTI + NW3 + NT2 + NOT;

  for (int i = blockIdx.x * blockDim.x + threadIdx.x; i < NT; i += gridDim.x * blockDim.x) {
    int j = i;
    if (j < NTI) {
      const int ct = j / 7168;
      const int e  = j - ct * 7168;
      if (e < 3072) {                    // w1 frag f = nt*3+ks
        const int f  = e >> 9, li = (e >> 3) & 63, el = e & 7;
        const int nt = f / 3, ks = f - nt * 3;
        const int n  = ct * 64 + nt * 32 + (li & 31);
        const int k  = ks * 16 + (li >> 5) * 8 + el;
        float val = 0.f;
        const float S1 = g1[n] * rsqrtf(v1[n] + EPSV);
        if (k < 36)       val = rW1[(size_t)k * 768 + n] * S1;
        else if (k == 36) val = (rb1[n] - m1[n]) * S1 + be1[n];
        tiles[j] = (_Float16)val;
      } else {                           // w2 frag f = n2t*4+kc
        const int e2 = e - 3072;
        const int f  = e2 >> 9, li = (e2 >> 3) & 63, el = e2 & 7;
        const int n2t = f >> 2, kc = f & 3;
        const int n2 = n2t * 32 + (li & 31);
        const int k  = ct * 64 + kc * 16 + (li >> 5) * 8 + el;
        const float S2 = g2[n2] * rsqrtf(v2[n2] + EPSV);
        tiles[j] = (_Float16)(rW2[(size_t)k * 64 + n2] * S2);
      }
      continue;
    }
    j -= NTI;
    if (j < NW3) {                       // w3 frag f3 = kc (n3 padded 16->32)
      const int f3 = j >> 9, li = (j >> 3) & 63, el = j & 7;
      const int n3 = li & 31;
      const int k  = f3 * 16 + (li >> 5) * 8 + el;
      w3t[j] = (n3 < 16) ? (_Float16)rW3[(size_t)k * 16 + n3] : (_Float16)0.f;
      continue;
    }
    j -= NW3;
    if (j < NT2) {
      const float S2 = g2[j] * rsqrtf(v2[j] + EPSV);
      t2o[j] = (rb2[j] - m2[j]) * S2 + be2[j];
      continue;
    }
    j -= NT2;
    {                                    // otab[f][v] = full per-feature MLP
      const int f = j >> 2, v = j & 3;
      const float* ev  = E + ((f << 2) + v) * 12;
      const float* w1f = W1 + f * 144;
      float emb[12];
      #pragma unroll
      for (int d = 0; d < 12; ++d) emb[d] = ev[d];
      float acc_o = b2[f];
      #pragma unroll
      for (int ee = 0; ee < 12; ++ee) {
        float h = b1[f * 12 + ee];
        #pragma unroll
        for (int d = 0; d < 12; ++d) h = fmaf(emb[d], w1f[d * 12 + ee], h);
        h = fmaxf(h, 0.f);
        acc_o = fmaf(h, W2[f * 12 + ee], acc_o);
      }
      otab[f * 4 + v] = fmaxf(acc_o, 0.f);
    }
  }
}

__device__ __forceinline__ float feat_val(const float* xv, const float* otab, int c) {
  if (c < 7)  return xv[c];
  if (c < 36) return otab[(c - 7) * 4 + (int)xv[c]];
  if (c == 36) return 1.0f;              // BN1-shift constant column
  return 0.f;
}

// stage one 14336 B chunk into LDS, once per block: 14 frags split across
// the 4 waves (f = w+4i); dest = wave-uniform base + lane*16 (the
// global_load_lds pattern). Issue-only; completion via __syncthreads().
__device__ __forceinline__ void stage_chunk(const char* gsrc, lds_char* ldst, int w, int l) {
  #pragma unroll
  for (int i = 0; i < 4; ++i) {
    const int f = w + 4 * i;             // wave-uniform at runtime
    if (f < 14) {
      __builtin_amdgcn_global_load_lds(
          (const __attribute__((address_space(1))) unsigned int*)(gsrc + f * 1024 + (size_t)l * 16),
          (lds_uint*)(ldst + f * 1024),
          16, 0, 0);
    }
  }
}

// ------- main: 128 rows/block, 4 waves x 32 rows (single m-tile per wave),
// ------- LDS-staged stream (dbuf, prefetch 1 ahead), 3 blocks/CU ----------
__global__ __launch_bounds__(256, 3)
void fused_mfma_kernel(const float* __restrict__ x,
                       const float* __restrict__ rb3,
                       const float* __restrict__ rW4,
                       const float* __restrict__ rb4,
                       const char* __restrict__ ws,
                       float* __restrict__ out)
{
  const int t  = threadIdx.x;
  const int w  = t >> 6;
  const int l  = t & 63;
  const int lm = l & 31;
  const int hi = l >> 5;

  // bijective XCD swizzle (grid=1024, 1024%8==0): output-invariant remap
  const int nwg = gridDim.x;
  const int bid = (blockIdx.x & 7) * (nwg >> 3) + (blockIdx.x >> 3);
  const int b0 = bid * 128;
  const int row = b0 + w * 32 + lm;     // lanes l and l+32 share one row

  __shared__ __align__(16) char smem[2 * CHUNK_BYTES];   // 28672 B
  lds_char* lds0 = (lds_char*)smem;

  const char* tiles = ws + OFF_TILES;

  // issue chunk-0 prefetch immediately; Phase A hides the latency
  stage_chunk(tiles, lds0, w, l);

  // ---- Phase A: own row -> 24 packed words, entirely in registers ----
  unsigned wbits[24];
  {
    const float* xr = x + (size_t)row * 36;
    float xv[36];
    #pragma unroll
    for (int i = 0; i < 9; ++i) {
      float4 v = *(const float4*)(xr + 4 * i);
      xv[4 * i + 0] = v.x; xv[4 * i + 1] = v.y;
      xv[4 * i + 2] = v.z; xv[4 * i + 3] = v.w;
    }
    const float* otab = (const float*)(ws + OFF_OTAB);
    #pragma unroll
    for (int c2 = 0; c2 < 19; ++c2)
      wbits[c2] = pk2(feat_val(xv, otab, 2 * c2), feat_val(xv, otab, 2 * c2 + 1));
    #pragma unroll
    for (int c2 = 19; c2 < 24; ++c2) wbits[c2] = 0u;
  }

  // ---- xf: B-frag (col=lane&31 -> row lm; k = ks*16 + hi*8 + e). Row is
  // lane-local: word q of ks = wbits[ks*8 + hi*4 + q] — compile-time
  // indices (rule #20), uniform hi select. (R13-verified bit-exact.)
  half8 xf[3];
  #pragma unroll
  for (int ks = 0; ks < 3; ++ks) {
    unsigned wq[4];
    #pragma unroll
    for (int q = 0; q < 4; ++q)
      wq[q] = hi ? wbits[ks * 8 + 4 + q] : wbits[ks * 8 + q];
    uintx4 u = {wq[0], wq[1], wq[2], wq[3]};
    xf[ks] = __builtin_bit_cast(half8, u);
  }

  // chunk-0 staged (syncthreads drains the global_load_lds queue)
  __syncthreads();

  floatx16 acc0 = zero16(), acc1 = zero16();

  #pragma unroll
  for (int ct = 0; ct < 12; ++ct) {
    const char* cbuf = smem + (ct & 1) * CHUNK_BYTES;

    // prefetch next chunk BEFORE compute; the MFMA body below hides the L2
    // latency; drained by this iteration's __syncthreads. (R14-verified.)
    if (ct < 11)
      stage_chunk(tiles + (size_t)(ct + 1) * CHUNK_BYTES,
                  lds0 + ((ct + 1) & 1) * CHUNK_BYTES, w, l);

    // LDS -> regs: contiguous lane*16 ds_read_b128 (conflict-free)
    const char* srcl = cbuf + (size_t)l * 16;
    half8 w1c[6], w2c[8];
    #pragma unroll
    for (int f = 0; f < 6; ++f)
      w1c[f] = *(const half8*)(srcl + f * 1024);
    #pragma unroll
    for (int f = 0; f < 8; ++f)
      w2c[f] = *(const half8*)(srcl + 6144 + f * 1024);

    __builtin_amdgcn_s_setprio(1);
    // ---- Phase 1: both GEMM1 half-chunks up front — 2 independent
    // ---- 3-deep MFMA chains (R7-style hoist on the single-m-tile base)
    floatx16 p0 = zero16(), p1 = zero16();
    #pragma unroll
    for (int ks = 0; ks < 3; ++ks) {
      p0 = __builtin_amdgcn_mfma_f32_32x32x16_f16(w1c[ks],     xf[ks], p0, 0, 0, 0);
      p1 = __builtin_amdgcn_mfma_f32_32x32x16_f16(w1c[3 + ks], xf[ks], p1, 0, 0, 0);
    }
    // ---- Phase 2: pack + GEMM2, kc order 0,1,2,3 (accumulation order
    // ---- IDENTICAL to R13's verified baseline)
    #pragma unroll
    for (int nt = 0; nt < 2; ++nt) {
      const floatx16 c1m = nt ? p1 : p0;        // compile-time select (rule #20)
      #pragma unroll
      for (int hf = 0; hf < 2; ++hf) {
        const int kc = nt * 2 + hf;
        const int b = hf * 8;
        half8 bf = mk_bfrag(c1m[b+0], c1m[b+1], c1m[b+2], c1m[b+3],
                            c1m[b+4], c1m[b+5], c1m[b+6], c1m[b+7]);
        acc0 = __builtin_amdgcn_mfma_f32_32x32x16_f16(w2c[0 * 4 + kc], bf, acc0, 0, 0, 0);
        acc1 = __builtin_amdgcn_mfma_f32_32x32x16_f16(w2c[1 * 4 + kc], bf, acc1, 0, 0, 0);
      }
    }
    __builtin_amdgcn_s_setprio(0);

    // rendezvous: next iter reads buf[(ct+1)&1] (just staged) and overwrites
    // buf[ct&1] (its reads above completed before any wave passes)
    if (ct < 11)
      __syncthreads();
  }

  // ---- Epilogue: +T2, relu, GEMM3 (w3 frags from L2), final dot + sigmoid ----
  const float* T2p = (const float*)(ws + OFF_T2);
  const _Float16* gW3 = (const _Float16*)(ws + OFF_W3);
  floatx16 c3 = zero16();

  #pragma unroll
  for (int n2t = 0; n2t < 2; ++n2t) {
    const floatx16 am = n2t ? acc1 : acc0;
    float h0[16];
    #pragma unroll
    for (int r = 0; r < 16; ++r) {
      const float t2v = T2p[n2t * 32 + (r & 3) + 8 * (r >> 2) + 4 * hi];
      h0[r] = fmaxf(am[r] + t2v, 0.f);
    }
    #pragma unroll
    for (int hf = 0; hf < 2; ++hf) {
      const int kc = n2t * 2 + hf;
      const int b = hf * 8;
      half8 bf = mk_bfrag(h0[b+0], h0[b+1], h0[b+2], h0[b+3],
                          h0[b+4], h0[b+5], h0[b+6], h0[b+7]);
      half8 a3 = *(const half8*)&gW3[(kc * 64 + l) * 8];
      c3 = __builtin_amdgcn_mfma_f32_32x32x16_f16(a3, bf, c3, 0, 0, 0);
    }
  }
  {
    float s0 = 0.f;
    const float bb = rb4[0];
    #pragma unroll
    for (int r = 0; r < 8; ++r) {
      const int n3 = (r & 3) + 8 * (r >> 2) + 4 * hi;
      s0 += fmaxf(c3[r] + rb3[n3], 0.f) * rW4[n3];
    }
    s0 += __shfl_xor(s0, 32, 64);
    if (hi == 0)
      out[row] = 1.f / (1.f + expf(-(s0 + bb)));
  }
}

extern "C" void kernel_launch(void* const* d_in, const int* in_sizes, int n_in,
                              void* d_out, int out_size, void* d_ws, size_t ws_size,
                              hipStream_t stream) {
  const float* x   = (const float*)d_in[0];
  const float* E   = (const float*)d_in[1];
  const float* W1  = (const float*)d_in[2];
  const float* b1  = (const float*)d_in[3];
  const float* W2  = (const float*)d_in[4];
  const float* b2  = (const float*)d_in[5];
  const float* rW1 = (const float*)d_in[6];
  const float* rb1 = (const float*)d_in[7];
  const float* g1  = (const float*)d_in[8];
  const float* be1 = (const float*)d_in[9];
  const float* m1  = (const float*)d_in[10];
  const float* v1  = (const float*)d_in[11];
  const float* rW2 = (const float*)d_in[12];
  const float* rb2 = (const float*)d_in[13];
  const float* g2  = (const float*)d_in[14];
  const float* be2 = (const float*)d_in[15];
  const float* m2  = (const float*)d_in[16];
  const float* v2  = (const float*)d_in[17];
  const float* rW3 = (const float*)d_in[18];
  const float* rb3 = (const float*)d_in[19];
  const float* rW4 = (const float*)d_in[20];
  const float* rb4 = (const float*)d_in[21];
  float* out = (float*)d_out;
  char* ws = (char*)d_ws;

  prep_kernel<<<128, 256, 0, stream>>>(E, W1, b1, W2, b2,
                                       rW1, rb1, g1, be1, m1, v1,
                                       rW2, rb2, g2, be2, m2, v2,
                                       rW3, ws);

  const int B = in_sizes[0] / 36;     // 131072
  dim3 grid(B / 128), block(256);
  fused_mfma_kernel<<<grid, block, 0, stream>>>(x, rb3, rW4, rb4, ws, out);
}